// Round 6
// baseline (6608.765 us; speedup 1.0000x reference)
//
#include <hip/hip_runtime.h>
#include <cstdint>
#include <cstddef>

// Problem constants: T,N,E,P,D,F = 24,10000,320000,20000,64,32
#define T_ 24
#define N_ 10000
#define E_ 320000
#define P_ 20000
#define D_ 64
#define F_ 32
#define XS_ 34   // x last-dim stride (F+2)

#define SCOPE_AGENT __HIP_MEMORY_SCOPE_AGENT

// ---- sc1 (L2-write-through) STORE helpers: shared mutable buffers only ----
__device__ __forceinline__ void stsc(float* p, float v) {
  __hip_atomic_store(p, v, __ATOMIC_RELAXED, SCOPE_AGENT);
}
__device__ __forceinline__ void stsc2(float* p, float a, float b) {
  unsigned long long u =
      ((unsigned long long)__float_as_uint(b) << 32) | (unsigned long long)__float_as_uint(a);
  __hip_atomic_store((unsigned long long*)p, u, __ATOMIC_RELAXED, SCOPE_AGENT);
}

// ---------------------------------------------------------------- preprocessing

__global__ void deg_kernel(const int* __restrict__ src, const int* __restrict__ dst,
                           int* __restrict__ deg_out, int* __restrict__ deg_in) {
  int e = blockIdx.x * blockDim.x + threadIdx.x;
  if (e < E_) {
    atomicAdd(&deg_out[src[e]], 1);
    atomicAdd(&deg_in[dst[e]], 1);
  }
}

__global__ void norm_kernel(const int* __restrict__ deg_in, const int* __restrict__ deg_out,
                            float* __restrict__ in_norm, float* __restrict__ out_norm) {
  int n = blockIdx.x * blockDim.x + threadIdx.x;
  if (n < N_) {
    in_norm[n]  = 1.0f / sqrtf(fmaxf((float)deg_in[n], 1.0f));
    out_norm[n] = 1.0f / sqrtf(fmaxf((float)deg_out[n], 1.0f));
  }
}

__global__ __launch_bounds__(1024) void scan_kernel(const int* __restrict__ deg,
                                                    int* __restrict__ row_ptr) {
  __shared__ int buf[1024];
  __shared__ int carry;
  int tid = threadIdx.x;
  if (tid == 0) { carry = 0; row_ptr[0] = 0; }
  __syncthreads();
  for (int base = 0; base < N_; base += 1024) {
    int i = base + tid;
    int v = (i < N_) ? deg[i] : 0;
    buf[tid] = v;
    __syncthreads();
    for (int off = 1; off < 1024; off <<= 1) {
      int tv = (tid >= off) ? buf[tid - off] : 0;
      __syncthreads();
      buf[tid] += tv;
      __syncthreads();
    }
    if (i < N_) row_ptr[i + 1] = carry + buf[tid];
    __syncthreads();
    if (tid == 0) carry += buf[1023];
    __syncthreads();
  }
}

__global__ void fill_kernel(const int* __restrict__ src, const int* __restrict__ dst,
                            const int* __restrict__ row_ptr, int* __restrict__ fill,
                            int* __restrict__ col) {
  int e = blockIdx.x * blockDim.x + threadIdx.x;
  if (e < E_) {
    int n = dst[e];
    int pos = row_ptr[n] + atomicAdd(&fill[n], 1);
    col[pos] = src[e];
  }
}

__global__ void dvec_kernel(const float* __restrict__ dis, const int* __restrict__ ti,
                            float* __restrict__ dvec) {
  int p = blockIdx.x * blockDim.x + threadIdx.x;
  if (p < P_) {
    int i0 = ti[p];
    int i1 = ti[P_ + p];
    dvec[p] = dis[(size_t)i0 * N_ + i1];
  }
}

// ---------------------------------------------------------------- mega kernel

struct Args {
  const float* x;
  const int* row_ptr;
  const int* col;
  const float* in_norm;
  const float* out_norm;
  const float* ruW1; const float* ruB1;
  const float* ruW2; const float* ruB2;
  const float* ruW3; const float* ruB3;
  const float* rhW1; const float* rhB1;
  const float* rhW2; const float* rhB2;
  const float* rhW3; const float* rhB3;
  const float* pW; const float* pb;
  const int* ti; const float* dvec;
  float* h; float* z; float* tA; float* tB;
  float* out;
  unsigned* barCnt;
};

// grid barrier + epoch cache-invalidate.
// Producers: sc1 stores are at the L3 coherence point once vmcnt drains
// (__syncthreads on arrival). Consumers: acquire-fence(agent) after release
// from the spin emits buffer_inv sc1 (drops any stale L1/L2 lines), so
// subsequent CACHED loads refetch current values from L3.
__device__ __forceinline__ void gbar(unsigned* cnt, unsigned nblk, unsigned& ep) {
  __syncthreads();
  ++ep;
  if (threadIdx.x == 0) {
    __hip_atomic_fetch_add(cnt, 1u, __ATOMIC_RELAXED, SCOPE_AGENT);
    unsigned target = ep * nblk;
    while (__hip_atomic_load(cnt, __ATOMIC_RELAXED, SCOPE_AGENT) < target)
      __builtin_amdgcn_s_sleep(8);
  }
  __syncthreads();
  __builtin_amdgcn_fence(__ATOMIC_ACQUIRE, "agent");  // buffer_inv sc1
}

__device__ __forceinline__ void stageW(const float* __restrict__ W, int n4,
                                       float4* __restrict__ sdst, int tid) {
  const float4* Wv = (const float4*)W;
  for (int i = tid; i < n4; i += 512) sdst[i] = Wv[i];
}

// CSR gather of 64-wide rows from tsrc — cached float4 loads (L2/L1 reuse:
// each source row is read ~32x per phase). 4 edge slices (g), float4 sub.
__device__ __forceinline__ float4 gatherNode(const float* __restrict__ tsrc,
                                             const int* __restrict__ rp,
                                             const int* __restrict__ col,
                                             int n, int g, int sub) {
  int e0 = rp[n], e1 = rp[n + 1];
  float4 acc = make_float4(0.f, 0.f, 0.f, 0.f);
  int e = e0 + g;
  int c0 = (e < e1) ? col[e] : 0;
  int c1 = (e + 4 < e1) ? col[e + 4] : 0;
  while (e < e1) {
    bool has1 = (e + 4 < e1);
    float4 v0 = ((const float4*)(tsrc + (size_t)c0 * 64))[sub];
    float4 v1 = make_float4(0.f, 0.f, 0.f, 0.f);
    if (has1) v1 = ((const float4*)(tsrc + (size_t)c1 * 64))[sub];
    int c2 = (e + 8 < e1) ? col[e + 8] : 0;
    int c3 = (e + 12 < e1) ? col[e + 12] : 0;
    acc.x += v0.x + v1.x;
    acc.y += v0.y + v1.y;
    acc.z += v0.z + v1.z;
    acc.w += v0.w + v1.w;
    c0 = c2; c1 = c3; e += 8;
  }
#pragma unroll
  for (int off = 16; off < 64; off <<= 1) {
    acc.x += __shfl_xor(acc.x, off);
    acc.y += __shfl_xor(acc.y, off);
    acc.z += __shfl_xor(acc.z, off);
    acc.w += __shfl_xor(acc.w, off);
  }
  return acc;
}

__device__ __forceinline__ void predPhase(const Args& A, int t, int wgid, int WT,
                                          int g, int sub) {
  float4 w0 = ((const float4*)A.pW)[sub];
  float4 w1 = ((const float4*)(A.pW + 64))[sub];
  for (int q = wgid; q * 4 < P_; q += WT) {
    int p = q * 4 + g;
    bool valid = (p < P_);
    int i0 = valid ? A.ti[p] : 0;
    int i1 = valid ? A.ti[P_ + p] : 0;
    float4 a0 = ((const float4*)(A.h + (size_t)i0 * 64))[sub];
    float4 a1 = ((const float4*)(A.h + (size_t)i1 * 64))[sub];
    float part = a0.x * w0.x + a0.y * w0.y + a0.z * w0.z + a0.w * w0.w
               + a1.x * w1.x + a1.y * w1.y + a1.z * w1.z + a1.w * w1.w;
#pragma unroll
    for (int off = 1; off < 16; off <<= 1) part += __shfl_xor(part, off);
    if (valid && sub == 0) {
      float a = part + A.pb[0] + A.dvec[p] * A.pW[128];
      stsc(A.out + (size_t)p * T_ + t, tanhf(a));
    }
  }
}

// MODE 0: tdst[n] = (out_norm*relu(in_norm*agg + bias)) @ W      (W 64x64)
// MODE 1: tdst[n] = out_norm*relu(in_norm*agg + bias)            (no W)
// MODE 2: a = (in_norm*agg)@W + bias (64->128); r,z=sigmoid; z->A.z;
//         hr=r*h; fused pre: tdst[n] = (out_norm*[hr|xt]) @ Wpre
// MODE 3: a = (in_norm*agg)@W + bias (64->64); hn=tanh; h=z*h+(1-z)*hn;
//         if doPre: tdst[n] = (out_norm*[h_new|xnext]) @ Wpre
template<int MODE>
__device__ __forceinline__ void runPhase(
    const Args& A, const float* __restrict__ tsrc, float* __restrict__ tdst,
    const float* __restrict__ W, const float* __restrict__ bias,
    const float* __restrict__ Wpre, const float* __restrict__ xside,
    float4* sWv, float4* sWpreV, float (*sRow)[96], float4 (*sAgg4)[16],
    int tid, int nodeBase, int nodeEnd, bool doPre) {
  const int wave = tid >> 6;
  const int lane = tid & 63;
  const int g = lane >> 4;
  const int sub = lane & 15;

  if (MODE == 0) stageW(W, 64 * 64 / 4, sWv, tid);
  if (MODE == 2) { stageW(W, 64 * 128 / 4, sWv, tid); stageW(Wpre, 96 * 64 / 4, sWpreV, tid); }
  if (MODE == 3) { stageW(W, 64 * 64 / 4, sWv, tid); if (doPre) stageW(Wpre, 96 * 64 / 4, sWpreV, tid); }
  if (MODE != 1) __syncthreads();

  const float* sW = (const float*)sWv;
  const float* sWpre = (const float*)sWpreV;

  float4 b4 = make_float4(0.f, 0.f, 0.f, 0.f);
  float b0 = 0.f, b1 = 0.f;
  if (MODE == 0 || MODE == 1) {
    b4 = ((const float4*)bias)[sub];
  } else if (MODE == 2) {
    b0 = bias[lane]; b1 = bias[64 + lane];
  } else {
    b0 = bias[lane];
  }

  for (int n = nodeBase + wave; n < nodeEnd; n += 8) {
    float4 acc = gatherNode(tsrc, A.row_ptr, A.col, n, g, sub);
    float inn = A.in_norm[n];
    float on = A.out_norm[n];

    if (MODE == 0 || MODE == 1) {
      float4 val;
      val.x = on * fmaxf(inn * acc.x + b4.x, 0.0f);
      val.y = on * fmaxf(inn * acc.y + b4.y, 0.0f);
      val.z = on * fmaxf(inn * acc.z + b4.z, 0.0f);
      val.w = on * fmaxf(inn * acc.w + b4.w, 0.0f);
      if (MODE == 1) {
        if (g == 0) {
          stsc2(tdst + (size_t)n * 64 + 4 * sub, val.x, val.y);
          stsc2(tdst + (size_t)n * 64 + 4 * sub + 2, val.z, val.w);
        }
      } else {
        if (g == 0) sAgg4[wave][sub] = val;
        const float* sAgg = (const float*)&sAgg4[wave][0];
        float a = 0.0f;
#pragma unroll 8
        for (int i = 0; i < 64; ++i) a += sAgg[i] * sW[i * 64 + lane];
        stsc(tdst + (size_t)n * 64 + lane, a);
      }
    } else if (MODE == 2) {
      if (g == 0) {
        float4 val;
        val.x = inn * acc.x; val.y = inn * acc.y;
        val.z = inn * acc.z; val.w = inn * acc.w;
        sAgg4[wave][sub] = val;
      }
      const float* sAgg = (const float*)&sAgg4[wave][0];
      float a0 = b0, a1 = b1;
#pragma unroll 8
      for (int i = 0; i < 64; ++i) {
        float s = sAgg[i];
        a0 += s * sW[i * 128 + lane];
        a1 += s * sW[i * 128 + 64 + lane];
      }
      float r = 1.0f / (1.0f + expf(-a0));
      float zz = 1.0f / (1.0f + expf(-a1));
      stsc(A.z + (size_t)n * 64 + lane, zz);
      float hrv = r * A.h[(size_t)n * 64 + lane];
      sRow[wave][lane] = on * hrv;
      if (lane < 32) sRow[wave][64 + lane] = on * xside[(size_t)n * XS_ + lane];
      float a = 0.0f;
#pragma unroll 8
      for (int i = 0; i < 96; ++i) a += sRow[wave][i] * sWpre[i * 64 + lane];
      stsc(tdst + (size_t)n * 64 + lane, a);
    } else {  // MODE 3
      if (g == 0) {
        float4 val;
        val.x = inn * acc.x; val.y = inn * acc.y;
        val.z = inn * acc.z; val.w = inn * acc.w;
        sAgg4[wave][sub] = val;
      }
      const float* sAgg = (const float*)&sAgg4[wave][0];
      float a = b0;
#pragma unroll 8
      for (int i = 0; i < 64; ++i) a += sAgg[i] * sW[i * 64 + lane];
      float hn = tanhf(a);
      float zz = A.z[(size_t)n * 64 + lane];
      float hp = A.h[(size_t)n * 64 + lane];
      float hnew = zz * hp + (1.0f - zz) * hn;
      stsc(A.h + (size_t)n * 64 + lane, hnew);
      if (doPre) {
        sRow[wave][lane] = on * hnew;
        if (lane < 32) sRow[wave][64 + lane] = on * xside[(size_t)n * XS_ + lane];
        float ap = 0.0f;
#pragma unroll 8
        for (int i = 0; i < 96; ++i) ap += sRow[wave][i] * sWpre[i * 64 + lane];
        stsc(tdst + (size_t)n * 64 + lane, ap);
      }
    }
  }
}

__global__ __launch_bounds__(512, 4) void mega_kernel(Args A) {
  __shared__ float4 sWv[2048];      // 32 KB: per-phase main W
  __shared__ float4 sWpreV[1536];   // 24 KB: fused 96x64 pre W
  __shared__ float sRow[8][96];     // 3 KB
  __shared__ float4 sAgg4[8][16];   // 2 KB

  const int tid = threadIdx.x;
  const int wave = tid >> 6;
  const int lane = tid & 63;
  const int g = lane >> 4;
  const int sub = lane & 15;
  const unsigned nblk = gridDim.x;
  const int NPB = (N_ + nblk - 1) / nblk;
  const int nodeBase = blockIdx.x * NPB;
  int nodeEnd = nodeBase + NPB;
  if (nodeEnd > N_) nodeEnd = N_;
  const int wgid = blockIdx.x * 8 + wave;
  const int WT = nblk * 8;
  unsigned ep = 0;

  // ---- P0: tA = (out_norm*[0|x0]) @ ru_W1  (h = 0)
  stageW(A.ruW1, 96 * 64 / 4, sWpreV, tid);
  __syncthreads();
  {
    const float* sWpre = (const float*)sWpreV;
    for (int n = nodeBase + wave; n < nodeEnd; n += 8) {
      float on = A.out_norm[n];
      if (lane < 32) sRow[wave][64 + lane] = on * A.x[(size_t)n * XS_ + lane];
      float a = 0.0f;
#pragma unroll 8
      for (int i = 64; i < 96; ++i) a += sRow[wave][i] * sWpre[i * 64 + lane];
      stsc(A.tA + (size_t)n * 64 + lane, a);
    }
  }
  gbar(A.barCnt, nblk, ep);

  for (int t = 0; t < T_; ++t) {
    const float* xt  = A.x + (size_t)t * N_ * XS_;
    const float* xt1 = A.x + (size_t)(t + 1) * N_ * XS_;

    // P1: tA -> tB (ru layer1->2, pre-transformed) ; plus pred of step t-1
    runPhase<0>(A, A.tA, A.tB, A.ruW2, A.ruB1, nullptr, nullptr,
                sWv, sWpreV, sRow, sAgg4, tid, nodeBase, nodeEnd, false);
    if (t > 0) predPhase(A, t - 1, wgid, WT, g, sub);
    gbar(A.barCnt, nblk, ep);

    // P2: tB -> tA (ru layer2 act only)
    runPhase<1>(A, A.tB, A.tA, nullptr, A.ruB2, nullptr, nullptr,
                sWv, sWpreV, sRow, sAgg4, tid, nodeBase, nodeEnd, false);
    gbar(A.barCnt, nblk, ep);

    // P3: tA -> (z, hr) ; fused pre_rh -> tB
    runPhase<2>(A, A.tA, A.tB, A.ruW3, A.ruB3, A.rhW1, xt,
                sWv, sWpreV, sRow, sAgg4, tid, nodeBase, nodeEnd, false);
    gbar(A.barCnt, nblk, ep);

    // P4: tB -> tA (rh layer1->2)
    runPhase<0>(A, A.tB, A.tA, A.rhW2, A.rhB1, nullptr, nullptr,
                sWv, sWpreV, sRow, sAgg4, tid, nodeBase, nodeEnd, false);
    gbar(A.barCnt, nblk, ep);

    // P5: tA -> tB (rh layer2 act only)
    runPhase<1>(A, A.tA, A.tB, nullptr, A.rhB2, nullptr, nullptr,
                sWv, sWpreV, sRow, sAgg4, tid, nodeBase, nodeEnd, false);
    gbar(A.barCnt, nblk, ep);

    // P6: tB -> h update ; fused pre_ru(t+1) -> tA
    runPhase<3>(A, A.tB, A.tA, A.rhW3, A.rhB3, A.ruW1, xt1,
                sWv, sWpreV, sRow, sAgg4, tid, nodeBase, nodeEnd, t < T_ - 1);
    gbar(A.barCnt, nblk, ep);
  }

  // final prediction for t = T-1
  predPhase(A, T_ - 1, wgid, WT, g, sub);
}

// ---------------------------------------------------------------- launch

extern "C" void kernel_launch(void* const* d_in, const int* in_sizes, int n_in,
                              void* d_out, int out_size, void* d_ws, size_t ws_size,
                              hipStream_t stream) {
  const float* x      = (const float*)d_in[0];
  const float* dis    = (const float*)d_in[1];
  const int*   src    = (const int*)d_in[2];
  const int*   dst    = (const int*)d_in[3];
  const int*   ti     = (const int*)d_in[4];
  const float* ru_W1  = (const float*)d_in[5];
  const float* ru_b1  = (const float*)d_in[6];
  const float* ru_W2  = (const float*)d_in[7];
  const float* ru_b2  = (const float*)d_in[8];
  const float* ru_W3  = (const float*)d_in[9];
  const float* ru_b3  = (const float*)d_in[10];
  const float* rh_W1  = (const float*)d_in[11];
  const float* rh_b1  = (const float*)d_in[12];
  const float* rh_W2  = (const float*)d_in[13];
  const float* rh_b2  = (const float*)d_in[14];
  const float* rh_W3  = (const float*)d_in[15];
  const float* rh_b3  = (const float*)d_in[16];
  const float* pred_W = (const float*)d_in[17];
  const float* pred_b = (const float*)d_in[18];
  float* out = (float*)d_out;

  char* w = (char*)d_ws;
  auto alloc = [&](size_t bytes) -> void* {
    void* p = (void*)w;
    w += (bytes + 255) & ~(size_t)255;
    return p;
  };
  int*   row_ptr  = (int*)alloc((N_ + 1) * sizeof(int));
  int*   colv     = (int*)alloc(E_ * sizeof(int));
  int*   deg_in   = (int*)alloc(N_ * sizeof(int));
  int*   deg_out  = (int*)alloc(N_ * sizeof(int));
  int*   fillc    = (int*)alloc(N_ * sizeof(int));
  float* in_norm  = (float*)alloc(N_ * sizeof(float));
  float* out_norm = (float*)alloc(N_ * sizeof(float));
  float* dvec     = (float*)alloc(P_ * sizeof(float));
  float* h        = (float*)alloc((size_t)N_ * D_ * sizeof(float));
  float* z        = (float*)alloc((size_t)N_ * D_ * sizeof(float));
  float* tA       = (float*)alloc((size_t)N_ * D_ * sizeof(float));
  float* tB       = (float*)alloc((size_t)N_ * D_ * sizeof(float));
  unsigned* barCnt = (unsigned*)alloc(256);

  hipMemsetAsync(deg_in, 0, N_ * sizeof(int), stream);
  hipMemsetAsync(deg_out, 0, N_ * sizeof(int), stream);
  hipMemsetAsync(fillc, 0, N_ * sizeof(int), stream);
  hipMemsetAsync(h, 0, (size_t)N_ * D_ * sizeof(float), stream);
  hipMemsetAsync(barCnt, 0, 256, stream);

  deg_kernel<<<(E_ + 255) / 256, 256, 0, stream>>>(src, dst, deg_out, deg_in);
  norm_kernel<<<(N_ + 255) / 256, 256, 0, stream>>>(deg_in, deg_out, in_norm, out_norm);
  scan_kernel<<<1, 1024, 0, stream>>>(deg_in, row_ptr);
  fill_kernel<<<(E_ + 255) / 256, 256, 0, stream>>>(src, dst, row_ptr, fillc, colv);
  dvec_kernel<<<(P_ + 255) / 256, 256, 0, stream>>>(dis, ti, dvec);

  Args a;
  a.x = x; a.row_ptr = row_ptr; a.col = colv;
  a.in_norm = in_norm; a.out_norm = out_norm;
  a.ruW1 = ru_W1; a.ruB1 = ru_b1; a.ruW2 = ru_W2; a.ruB2 = ru_b2;
  a.ruW3 = ru_W3; a.ruB3 = ru_b3;
  a.rhW1 = rh_W1; a.rhB1 = rh_b1; a.rhW2 = rh_W2; a.rhB2 = rh_b2;
  a.rhW3 = rh_W3; a.rhB3 = rh_b3;
  a.pW = pred_W; a.pb = pred_b; a.ti = ti; a.dvec = dvec;
  a.h = h; a.z = z; a.tA = tA; a.tB = tB; a.out = out;
  a.barCnt = barCnt;

  // Grid must be co-resident (round-3 lesson: over-subscribed cooperative
  // launch fails silently -> zero output). Size from the occupancy API.
  int maxb = 0;
  hipOccupancyMaxActiveBlocksPerMultiprocessor(&maxb, mega_kernel, 512, 0);
  if (maxb < 1) maxb = 1;
  int bpc = (maxb < 2) ? maxb : 2;
  int nblk = 256 * bpc;

  void* params[] = { (void*)&a };
  hipError_t err = hipLaunchCooperativeKernel((const void*)mega_kernel, dim3(nblk),
                                              dim3(512), params, 0, stream);
  if (err != hipSuccess) {
    // Barrier is hand-rolled (no cg) and grid is co-resident by construction.
    mega_kernel<<<dim3(nblk), dim3(512), 0, stream>>>(a);
  }
}

// Round 8
// 4295.759 us; speedup vs baseline: 1.5384x; 1.5384x over previous
//
#include <hip/hip_runtime.h>
#include <cstdint>
#include <cstddef>

// Problem constants: T,N,E,P,D,F = 24,10000,320000,20000,64,32
#define T_ 24
#define N_ 10000
#define E_ 320000
#define P_ 20000
#define D_ 64
#define F_ 32
#define XS_ 34   // x last-dim stride (F+2)
#define NZROWS 64  // zero rows appended to tA/tB for tail-slot sentinel loads

#define SCOPE_AGENT __HIP_MEMORY_SCOPE_AGENT

typedef float f32x4 __attribute__((ext_vector_type(4)));  // native vector: legal in asm "v"

// ---- coherent access helpers ----------------------------------------------
// sc1 = device-scope: bypasses the (non-cross-coherent) per-XCD L2s, reads/
// writes the L3 coherence point. Stores: atomic intrinsic. Wide ops: asm with
// ext_vector operands (struct float4 is NOT asm-compatible — round-7 lesson).
__device__ __forceinline__ float ldsc(const float* p) {
  return __hip_atomic_load((const float*)p, __ATOMIC_RELAXED, SCOPE_AGENT);
}
__device__ __forceinline__ float2 ldsc2(const float* p) {
  unsigned long long u =
      __hip_atomic_load((const unsigned long long*)p, __ATOMIC_RELAXED, SCOPE_AGENT);
  float2 r;
  r.x = __uint_as_float((unsigned)(u & 0xffffffffu));
  r.y = __uint_as_float((unsigned)(u >> 32));
  return r;
}
__device__ __forceinline__ void stsc(float* p, float v) {
  __hip_atomic_store(p, v, __ATOMIC_RELAXED, SCOPE_AGENT);
}
__device__ __forceinline__ void stsc16(float* p, f32x4 v) {
  asm volatile("global_store_dwordx4 %0, %1, off sc1" :: "v"(p), "v"(v) : "memory");
}
__device__ __forceinline__ f32x4 ld4sc(const float* p) {
  f32x4 v;
  asm volatile("global_load_dwordx4 %0, %1, off sc1" : "=v"(v) : "v"(p));
  return v;
}
// wait for all issued loads; sched_barrier pins consuming ALU after the wait
// (rule #18: "memory" clobber alone does not order register-only uses)
__device__ __forceinline__ void vmwait0() {
  asm volatile("s_waitcnt vmcnt(0)" ::: "memory");
  __builtin_amdgcn_sched_barrier(0);
}

// ---------------------------------------------------------------- preprocessing

__global__ void deg_kernel(const int* __restrict__ src, const int* __restrict__ dst,
                           int* __restrict__ deg_out, int* __restrict__ deg_in) {
  int e = blockIdx.x * blockDim.x + threadIdx.x;
  if (e < E_) {
    atomicAdd(&deg_out[src[e]], 1);
    atomicAdd(&deg_in[dst[e]], 1);
  }
}

__global__ void norm_kernel(const int* __restrict__ deg_in, const int* __restrict__ deg_out,
                            float* __restrict__ in_norm, float* __restrict__ out_norm) {
  int n = blockIdx.x * blockDim.x + threadIdx.x;
  if (n < N_) {
    in_norm[n]  = 1.0f / sqrtf(fmaxf((float)deg_in[n], 1.0f));
    out_norm[n] = 1.0f / sqrtf(fmaxf((float)deg_out[n], 1.0f));
  }
}

__global__ __launch_bounds__(1024) void scan_kernel(const int* __restrict__ deg,
                                                    int* __restrict__ row_ptr) {
  __shared__ int buf[1024];
  __shared__ int carry;
  int tid = threadIdx.x;
  if (tid == 0) { carry = 0; row_ptr[0] = 0; }
  __syncthreads();
  for (int base = 0; base < N_; base += 1024) {
    int i = base + tid;
    int v = (i < N_) ? deg[i] : 0;
    buf[tid] = v;
    __syncthreads();
    for (int off = 1; off < 1024; off <<= 1) {
      int tv = (tid >= off) ? buf[tid - off] : 0;
      __syncthreads();
      buf[tid] += tv;
      __syncthreads();
    }
    if (i < N_) row_ptr[i + 1] = carry + buf[tid];
    __syncthreads();
    if (tid == 0) carry += buf[1023];
    __syncthreads();
  }
}

__global__ void fill_kernel(const int* __restrict__ src, const int* __restrict__ dst,
                            const int* __restrict__ row_ptr, int* __restrict__ fill,
                            int* __restrict__ col) {
  int e = blockIdx.x * blockDim.x + threadIdx.x;
  if (e < E_) {
    int n = dst[e];
    int pos = row_ptr[n] + atomicAdd(&fill[n], 1);
    col[pos] = src[e];
  }
}

__global__ void dvec_kernel(const float* __restrict__ dis, const int* __restrict__ ti,
                            float* __restrict__ dvec) {
  int p = blockIdx.x * blockDim.x + threadIdx.x;
  if (p < P_) {
    int i0 = ti[p];
    int i1 = ti[P_ + p];
    dvec[p] = dis[(size_t)i0 * N_ + i1];
  }
}

// ---------------------------------------------------------------- mega kernel

struct Args {
  const float* x;
  const int* row_ptr;
  const int* col;
  const float* in_norm;
  const float* out_norm;
  const float* ruW1; const float* ruB1;
  const float* ruW2; const float* ruB2;
  const float* ruW3; const float* ruB3;
  const float* rhW1; const float* rhB1;
  const float* rhW2; const float* rhB2;
  const float* rhW3; const float* rhB3;
  const float* pW; const float* pb;
  const int* ti; const float* dvec;
  float* h; float* z; float* tA; float* tB;
  float* out;
  unsigned* barCnt;
};

// grid barrier: no cache-maintenance; sc1 stores are at the coherence point
// once vmcnt drains (__syncthreads on arrival); sc1 loads always read the
// coherence point. Counter is monotone (never reset).
__device__ __forceinline__ void gbar(unsigned* cnt, unsigned nblk, unsigned& ep) {
  __syncthreads();
  ++ep;
  if (threadIdx.x == 0) {
    __hip_atomic_fetch_add(cnt, 1u, __ATOMIC_RELAXED, SCOPE_AGENT);
    unsigned target = ep * nblk;
    while (__hip_atomic_load(cnt, __ATOMIC_RELAXED, SCOPE_AGENT) < target)
      __builtin_amdgcn_s_sleep(8);
  }
  __syncthreads();
}

__device__ __forceinline__ void stageW(const float* __restrict__ W, int n4,
                                       float4* __restrict__ sdst, int tid) {
  const float4* Wv = (const float4*)W;
  for (int i = tid; i < n4; i += 512) sdst[i] = Wv[i];
}

// CSR gather of 64-wide rows from tsrc via sc1 dwordx4 loads, 8 in flight
// (covers a full average-degree node in one wait). Tail slots read per-node
// zero rows (rows N_..N_+63) to stay branch-free without a hot line.
__device__ __forceinline__ float4 gatherNode(const float* __restrict__ tsrc,
                                             const int* __restrict__ rp,
                                             const int* __restrict__ col,
                                             int n, int g, int sub) {
  const int zrow = N_ + (n & (NZROWS - 1));
  int e0 = rp[n], e1 = rp[n + 1];
  f32x4 acc = {0.f, 0.f, 0.f, 0.f};
  int e = e0 + g;
  while (e < e1) {
    int c0 = col[e];
    int c1 = (e + 4  < e1) ? col[e + 4]  : zrow;
    int c2 = (e + 8  < e1) ? col[e + 8]  : zrow;
    int c3 = (e + 12 < e1) ? col[e + 12] : zrow;
    int c4 = (e + 16 < e1) ? col[e + 16] : zrow;
    int c5 = (e + 20 < e1) ? col[e + 20] : zrow;
    int c6 = (e + 24 < e1) ? col[e + 24] : zrow;
    int c7 = (e + 28 < e1) ? col[e + 28] : zrow;
    f32x4 v0 = ld4sc(tsrc + (size_t)c0 * 64 + 4 * sub);
    f32x4 v1 = ld4sc(tsrc + (size_t)c1 * 64 + 4 * sub);
    f32x4 v2 = ld4sc(tsrc + (size_t)c2 * 64 + 4 * sub);
    f32x4 v3 = ld4sc(tsrc + (size_t)c3 * 64 + 4 * sub);
    f32x4 v4 = ld4sc(tsrc + (size_t)c4 * 64 + 4 * sub);
    f32x4 v5 = ld4sc(tsrc + (size_t)c5 * 64 + 4 * sub);
    f32x4 v6 = ld4sc(tsrc + (size_t)c6 * 64 + 4 * sub);
    f32x4 v7 = ld4sc(tsrc + (size_t)c7 * 64 + 4 * sub);
    e += 32;
    vmwait0();
    acc += ((v0 + v1) + (v2 + v3)) + ((v4 + v5) + (v6 + v7));
  }
  float ax = acc.x, ay = acc.y, az = acc.z, aw = acc.w;
#pragma unroll
  for (int off = 16; off < 64; off <<= 1) {
    ax += __shfl_xor(ax, off);
    ay += __shfl_xor(ay, off);
    az += __shfl_xor(az, off);
    aw += __shfl_xor(aw, off);
  }
  return make_float4(ax, ay, az, aw);
}

__device__ __forceinline__ void predPhase(const Args& A, int t, int wgid, int WT,
                                          int g, int sub) {
  const float2* pw2 = (const float2*)A.pW;
  float2 w00 = pw2[sub],      w01 = pw2[16 + sub];
  float2 w10 = pw2[32 + sub], w11 = pw2[48 + sub];
  for (int q = wgid; q * 4 < P_; q += WT) {
    int p = q * 4 + g;
    bool valid = (p < P_);
    int i0 = valid ? A.ti[p] : 0;
    int i1 = valid ? A.ti[P_ + p] : 0;
    const float* h0 = A.h + (size_t)i0 * 64 + 2 * sub;
    const float* h1 = A.h + (size_t)i1 * 64 + 2 * sub;
    float2 a00 = ldsc2(h0), a01 = ldsc2(h0 + 32);
    float2 a10 = ldsc2(h1), a11 = ldsc2(h1 + 32);
    float part = a00.x * w00.x + a00.y * w00.y + a01.x * w01.x + a01.y * w01.y
               + a10.x * w10.x + a10.y * w10.y + a11.x * w11.x + a11.y * w11.y;
#pragma unroll
    for (int off = 1; off < 16; off <<= 1) part += __shfl_xor(part, off);
    if (valid && sub == 0) {
      float a = part + A.pb[0] + A.dvec[p] * A.pW[128];
      stsc(A.out + (size_t)p * T_ + t, tanhf(a));
    }
  }
}

// MODE 0: tdst[n] = (out_norm*relu(in_norm*agg + bias)) @ W      (W 64x64)
// MODE 1: tdst[n] = out_norm*relu(in_norm*agg + bias)            (no W)
// MODE 2: a = (in_norm*agg)@W + bias (64->128); r,z=sigmoid; z->A.z;
//         hr=r*h; fused pre: tdst[n] = (out_norm*[hr|xt]) @ Wpre
// MODE 3: a = (in_norm*agg)@W + bias (64->64); hn=tanh; h=z*h+(1-z)*hn;
//         if doPre: tdst[n] = (out_norm*[h_new|xnext]) @ Wpre
template<int MODE>
__device__ __forceinline__ void runPhase(
    const Args& A, const float* __restrict__ tsrc, float* __restrict__ tdst,
    const float* __restrict__ W, const float* __restrict__ bias,
    const float* __restrict__ Wpre, const float* __restrict__ xside,
    float4* sWv, float4* sWpreV, float (*sRow)[96], float4 (*sAgg4)[16],
    int tid, int nodeBase, int nodeEnd, bool doPre) {
  const int wave = tid >> 6;
  const int lane = tid & 63;
  const int g = lane >> 4;
  const int sub = lane & 15;

  if (MODE == 0) stageW(W, 64 * 64 / 4, sWv, tid);
  if (MODE == 2) { stageW(W, 64 * 128 / 4, sWv, tid); stageW(Wpre, 96 * 64 / 4, sWpreV, tid); }
  if (MODE == 3) { stageW(W, 64 * 64 / 4, sWv, tid); if (doPre) stageW(Wpre, 96 * 64 / 4, sWpreV, tid); }
  if (MODE != 1) __syncthreads();

  const float* sW = (const float*)sWv;
  const float* sWpre = (const float*)sWpreV;

  float4 b4 = make_float4(0.f, 0.f, 0.f, 0.f);
  float b0 = 0.f, b1 = 0.f;
  if (MODE == 0 || MODE == 1) {
    b4 = ((const float4*)bias)[sub];
  } else if (MODE == 2) {
    b0 = bias[lane]; b1 = bias[64 + lane];
  } else {
    b0 = bias[lane];
  }

  for (int n = nodeBase + wave; n < nodeEnd; n += 8) {
    float4 acc = gatherNode(tsrc, A.row_ptr, A.col, n, g, sub);
    float inn = A.in_norm[n];
    float on = A.out_norm[n];

    if (MODE == 0 || MODE == 1) {
      float4 val;
      val.x = on * fmaxf(inn * acc.x + b4.x, 0.0f);
      val.y = on * fmaxf(inn * acc.y + b4.y, 0.0f);
      val.z = on * fmaxf(inn * acc.z + b4.z, 0.0f);
      val.w = on * fmaxf(inn * acc.w + b4.w, 0.0f);
      if (MODE == 1) {
        if (g == 0) {
          f32x4 vv = {val.x, val.y, val.z, val.w};
          stsc16(tdst + (size_t)n * 64 + 4 * sub, vv);
        }
      } else {
        if (g == 0) sAgg4[wave][sub] = val;
        const float* sAgg = (const float*)&sAgg4[wave][0];
        float a = 0.0f;
#pragma unroll 8
        for (int i = 0; i < 64; ++i) a += sAgg[i] * sW[i * 64 + lane];
        stsc(tdst + (size_t)n * 64 + lane, a);
      }
    } else if (MODE == 2) {
      if (g == 0) {
        float4 val;
        val.x = inn * acc.x; val.y = inn * acc.y;
        val.z = inn * acc.z; val.w = inn * acc.w;
        sAgg4[wave][sub] = val;
      }
      const float* sAgg = (const float*)&sAgg4[wave][0];
      float a0 = b0, a1 = b1;
#pragma unroll 8
      for (int i = 0; i < 64; ++i) {
        float s = sAgg[i];
        a0 += s * sW[i * 128 + lane];
        a1 += s * sW[i * 128 + 64 + lane];
      }
      float r = 1.0f / (1.0f + expf(-a0));
      float zz = 1.0f / (1.0f + expf(-a1));
      stsc(A.z + (size_t)n * 64 + lane, zz);
      float hrv = r * ldsc(A.h + (size_t)n * 64 + lane);
      sRow[wave][lane] = on * hrv;
      if (lane < 32) sRow[wave][64 + lane] = on * xside[(size_t)n * XS_ + lane];
      float a = 0.0f;
#pragma unroll 8
      for (int i = 0; i < 96; ++i) a += sRow[wave][i] * sWpre[i * 64 + lane];
      stsc(tdst + (size_t)n * 64 + lane, a);
    } else {  // MODE 3
      if (g == 0) {
        float4 val;
        val.x = inn * acc.x; val.y = inn * acc.y;
        val.z = inn * acc.z; val.w = inn * acc.w;
        sAgg4[wave][sub] = val;
      }
      const float* sAgg = (const float*)&sAgg4[wave][0];
      float a = b0;
#pragma unroll 8
      for (int i = 0; i < 64; ++i) a += sAgg[i] * sW[i * 64 + lane];
      float hn = tanhf(a);
      float zz = ldsc(A.z + (size_t)n * 64 + lane);
      float hp = ldsc(A.h + (size_t)n * 64 + lane);
      float hnew = zz * hp + (1.0f - zz) * hn;
      stsc(A.h + (size_t)n * 64 + lane, hnew);
      if (doPre) {
        sRow[wave][lane] = on * hnew;
        if (lane < 32) sRow[wave][64 + lane] = on * xside[(size_t)n * XS_ + lane];
        float ap = 0.0f;
#pragma unroll 8
        for (int i = 0; i < 96; ++i) ap += sRow[wave][i] * sWpre[i * 64 + lane];
        stsc(tdst + (size_t)n * 64 + lane, ap);
      }
    }
  }
}

__global__ __launch_bounds__(512, 4) void mega_kernel(Args A) {
  __shared__ float4 sWv[2048];      // 32 KB: per-phase main W
  __shared__ float4 sWpreV[1536];   // 24 KB: fused 96x64 pre W
  __shared__ float sRow[8][96];     // 3 KB
  __shared__ float4 sAgg4[8][16];   // 2 KB

  const int tid = threadIdx.x;
  const int wave = tid >> 6;
  const int lane = tid & 63;
  const int g = lane >> 4;
  const int sub = lane & 15;
  const unsigned nblk = gridDim.x;
  const int NPB = (N_ + nblk - 1) / nblk;
  const int nodeBase = blockIdx.x * NPB;
  int nodeEnd = nodeBase + NPB;
  if (nodeEnd > N_) nodeEnd = N_;
  const int wgid = blockIdx.x * 8 + wave;
  const int WT = nblk * 8;
  unsigned ep = 0;

  // ---- P0: tA = (out_norm*[0|x0]) @ ru_W1  (h = 0)
  stageW(A.ruW1, 96 * 64 / 4, sWpreV, tid);
  __syncthreads();
  {
    const float* sWpre = (const float*)sWpreV;
    for (int n = nodeBase + wave; n < nodeEnd; n += 8) {
      float on = A.out_norm[n];
      if (lane < 32) sRow[wave][64 + lane] = on * A.x[(size_t)n * XS_ + lane];
      float a = 0.0f;
#pragma unroll 8
      for (int i = 64; i < 96; ++i) a += sRow[wave][i] * sWpre[i * 64 + lane];
      stsc(A.tA + (size_t)n * 64 + lane, a);
    }
  }
  gbar(A.barCnt, nblk, ep);

  for (int t = 0; t < T_; ++t) {
    const float* xt  = A.x + (size_t)t * N_ * XS_;
    const float* xt1 = A.x + (size_t)(t + 1) * N_ * XS_;

    // P1: tA -> tB (ru layer1->2, pre-transformed) ; plus pred of step t-1
    runPhase<0>(A, A.tA, A.tB, A.ruW2, A.ruB1, nullptr, nullptr,
                sWv, sWpreV, sRow, sAgg4, tid, nodeBase, nodeEnd, false);
    if (t > 0) predPhase(A, t - 1, wgid, WT, g, sub);
    gbar(A.barCnt, nblk, ep);

    // P2: tB -> tA (ru layer2 act only)
    runPhase<1>(A, A.tB, A.tA, nullptr, A.ruB2, nullptr, nullptr,
                sWv, sWpreV, sRow, sAgg4, tid, nodeBase, nodeEnd, false);
    gbar(A.barCnt, nblk, ep);

    // P3: tA -> (z, hr) ; fused pre_rh -> tB
    runPhase<2>(A, A.tA, A.tB, A.ruW3, A.ruB3, A.rhW1, xt,
                sWv, sWpreV, sRow, sAgg4, tid, nodeBase, nodeEnd, false);
    gbar(A.barCnt, nblk, ep);

    // P4: tB -> tA (rh layer1->2)
    runPhase<0>(A, A.tB, A.tA, A.rhW2, A.rhB1, nullptr, nullptr,
                sWv, sWpreV, sRow, sAgg4, tid, nodeBase, nodeEnd, false);
    gbar(A.barCnt, nblk, ep);

    // P5: tA -> tB (rh layer2 act only)
    runPhase<1>(A, A.tA, A.tB, nullptr, A.rhB2, nullptr, nullptr,
                sWv, sWpreV, sRow, sAgg4, tid, nodeBase, nodeEnd, false);
    gbar(A.barCnt, nblk, ep);

    // P6: tB -> h update ; fused pre_ru(t+1) -> tA
    runPhase<3>(A, A.tB, A.tA, A.rhW3, A.rhB3, A.ruW1, xt1,
                sWv, sWpreV, sRow, sAgg4, tid, nodeBase, nodeEnd, t < T_ - 1);
    gbar(A.barCnt, nblk, ep);
  }

  // final prediction for t = T-1
  predPhase(A, T_ - 1, wgid, WT, g, sub);
}

// ---------------------------------------------------------------- launch

extern "C" void kernel_launch(void* const* d_in, const int* in_sizes, int n_in,
                              void* d_out, int out_size, void* d_ws, size_t ws_size,
                              hipStream_t stream) {
  const float* x      = (const float*)d_in[0];
  const float* dis    = (const float*)d_in[1];
  const int*   src    = (const int*)d_in[2];
  const int*   dst    = (const int*)d_in[3];
  const int*   ti     = (const int*)d_in[4];
  const float* ru_W1  = (const float*)d_in[5];
  const float* ru_b1  = (const float*)d_in[6];
  const float* ru_W2  = (const float*)d_in[7];
  const float* ru_b2  = (const float*)d_in[8];
  const float* ru_W3  = (const float*)d_in[9];
  const float* ru_b3  = (const float*)d_in[10];
  const float* rh_W1  = (const float*)d_in[11];
  const float* rh_b1  = (const float*)d_in[12];
  const float* rh_W2  = (const float*)d_in[13];
  const float* rh_b2  = (const float*)d_in[14];
  const float* rh_W3  = (const float*)d_in[15];
  const float* rh_b3  = (const float*)d_in[16];
  const float* pred_W = (const float*)d_in[17];
  const float* pred_b = (const float*)d_in[18];
  float* out = (float*)d_out;

  char* w = (char*)d_ws;
  auto alloc = [&](size_t bytes) -> void* {
    void* p = (void*)w;
    w += (bytes + 255) & ~(size_t)255;
    return p;
  };
  int*   row_ptr  = (int*)alloc((N_ + 1) * sizeof(int));
  int*   colv     = (int*)alloc(E_ * sizeof(int));
  int*   deg_in   = (int*)alloc(N_ * sizeof(int));
  int*   deg_out  = (int*)alloc(N_ * sizeof(int));
  int*   fillc    = (int*)alloc(N_ * sizeof(int));
  float* in_norm  = (float*)alloc(N_ * sizeof(float));
  float* out_norm = (float*)alloc(N_ * sizeof(float));
  float* dvec     = (float*)alloc(P_ * sizeof(float));
  float* h        = (float*)alloc((size_t)N_ * D_ * sizeof(float));
  float* z        = (float*)alloc((size_t)N_ * D_ * sizeof(float));
  float* tA       = (float*)alloc((size_t)(N_ + NZROWS) * D_ * sizeof(float));
  float* tB       = (float*)alloc((size_t)(N_ + NZROWS) * D_ * sizeof(float));
  unsigned* barCnt = (unsigned*)alloc(256);

  (void)hipMemsetAsync(deg_in, 0, N_ * sizeof(int), stream);
  (void)hipMemsetAsync(deg_out, 0, N_ * sizeof(int), stream);
  (void)hipMemsetAsync(fillc, 0, N_ * sizeof(int), stream);
  (void)hipMemsetAsync(h, 0, (size_t)N_ * D_ * sizeof(float), stream);
  (void)hipMemsetAsync(tA + (size_t)N_ * D_, 0, (size_t)NZROWS * D_ * sizeof(float), stream);
  (void)hipMemsetAsync(tB + (size_t)N_ * D_, 0, (size_t)NZROWS * D_ * sizeof(float), stream);
  (void)hipMemsetAsync(barCnt, 0, 256, stream);

  deg_kernel<<<(E_ + 255) / 256, 256, 0, stream>>>(src, dst, deg_out, deg_in);
  norm_kernel<<<(N_ + 255) / 256, 256, 0, stream>>>(deg_in, deg_out, in_norm, out_norm);
  scan_kernel<<<1, 1024, 0, stream>>>(deg_in, row_ptr);
  fill_kernel<<<(E_ + 255) / 256, 256, 0, stream>>>(src, dst, row_ptr, fillc, colv);
  dvec_kernel<<<(P_ + 255) / 256, 256, 0, stream>>>(dis, ti, dvec);

  Args a;
  a.x = x; a.row_ptr = row_ptr; a.col = colv;
  a.in_norm = in_norm; a.out_norm = out_norm;
  a.ruW1 = ru_W1; a.ruB1 = ru_b1; a.ruW2 = ru_W2; a.ruB2 = ru_b2;
  a.ruW3 = ru_W3; a.ruB3 = ru_b3;
  a.rhW1 = rh_W1; a.rhB1 = rh_b1; a.rhW2 = rh_W2; a.rhB2 = rh_b2;
  a.rhW3 = rh_W3; a.rhB3 = rh_b3;
  a.pW = pred_W; a.pb = pred_b; a.ti = ti; a.dvec = dvec;
  a.h = h; a.z = z; a.tA = tA; a.tB = tB; a.out = out;
  a.barCnt = barCnt;

  // Grid must be co-resident (round-3 lesson: over-subscribed cooperative
  // launch fails silently -> zero output). Size from the occupancy API.
  int maxb = 0;
  (void)hipOccupancyMaxActiveBlocksPerMultiprocessor(&maxb, mega_kernel, 512, 0);
  if (maxb < 1) maxb = 1;
  int bpc = (maxb < 2) ? maxb : 2;
  int nblk = 256 * bpc;

  void* params[] = { (void*)&a };
  hipError_t err = hipLaunchCooperativeKernel((const void*)mega_kernel, dim3(nblk),
                                              dim3(512), params, 0, stream);
  if (err != hipSuccess) {
    // Barrier is hand-rolled (no cg) and grid is co-resident by construction.
    mega_kernel<<<dim3(nblk), dim3(512), 0, stream>>>(a);
  }
}

// Round 9
// 3340.872 us; speedup vs baseline: 1.9782x; 1.2858x over previous
//
#include <hip/hip_runtime.h>
#include <cstdint>
#include <cstddef>

// Problem constants: T,N,E,P,D,F = 24,10000,320000,20000,64,32
#define T_ 24
#define N_ 10000
#define E_ 320000
#define P_ 20000
#define D_ 64
#define F_ 32
#define XS_ 34   // x last-dim stride (F+2)
#define NZROWS 64  // zero rows appended to tA/tB for tail-slot sentinel loads

#define SCOPE_AGENT __HIP_MEMORY_SCOPE_AGENT

typedef float f32x4 __attribute__((ext_vector_type(4)));  // native vector: legal in asm "v"

// ---- coherent access helpers ----------------------------------------------
// sc1 = device-scope: bypasses the (non-cross-coherent) per-XCD L2s, reads/
// writes the L3 coherence point. Stores: atomic intrinsic. Wide ops: asm with
// ext_vector operands (struct float4 is NOT asm-compatible — round-7 lesson).
__device__ __forceinline__ float ldsc(const float* p) {
  return __hip_atomic_load((const float*)p, __ATOMIC_RELAXED, SCOPE_AGENT);
}
__device__ __forceinline__ float2 ldsc2(const float* p) {
  unsigned long long u =
      __hip_atomic_load((const unsigned long long*)p, __ATOMIC_RELAXED, SCOPE_AGENT);
  float2 r;
  r.x = __uint_as_float((unsigned)(u & 0xffffffffu));
  r.y = __uint_as_float((unsigned)(u >> 32));
  return r;
}
__device__ __forceinline__ void stsc(float* p, float v) {
  __hip_atomic_store(p, v, __ATOMIC_RELAXED, SCOPE_AGENT);
}
__device__ __forceinline__ void stsc16(float* p, f32x4 v) {
  asm volatile("global_store_dwordx4 %0, %1, off sc1" :: "v"(p), "v"(v) : "memory");
}
__device__ __forceinline__ f32x4 ld4sc(const float* p) {
  f32x4 v;
  asm volatile("global_load_dwordx4 %0, %1, off sc1" : "=v"(v) : "v"(p));
  return v;
}
// wait for all issued loads; sched_barrier pins consuming ALU after the wait
__device__ __forceinline__ void vmwait0() {
  asm volatile("s_waitcnt vmcnt(0)" ::: "memory");
  __builtin_amdgcn_sched_barrier(0);
}

// ---------------------------------------------------------------- preprocessing

__global__ void deg_kernel(const int* __restrict__ src, const int* __restrict__ dst,
                           int* __restrict__ deg_out, int* __restrict__ deg_in) {
  int e = blockIdx.x * blockDim.x + threadIdx.x;
  if (e < E_) {
    atomicAdd(&deg_out[src[e]], 1);
    atomicAdd(&deg_in[dst[e]], 1);
  }
}

__global__ void norm_kernel(const int* __restrict__ deg_in, const int* __restrict__ deg_out,
                            float* __restrict__ in_norm, float* __restrict__ out_norm) {
  int n = blockIdx.x * blockDim.x + threadIdx.x;
  if (n < N_) {
    in_norm[n]  = 1.0f / sqrtf(fmaxf((float)deg_in[n], 1.0f));
    out_norm[n] = 1.0f / sqrtf(fmaxf((float)deg_out[n], 1.0f));
  }
}

__global__ __launch_bounds__(1024) void scan_kernel(const int* __restrict__ deg,
                                                    int* __restrict__ row_ptr) {
  __shared__ int buf[1024];
  __shared__ int carry;
  int tid = threadIdx.x;
  if (tid == 0) { carry = 0; row_ptr[0] = 0; }
  __syncthreads();
  for (int base = 0; base < N_; base += 1024) {
    int i = base + tid;
    int v = (i < N_) ? deg[i] : 0;
    buf[tid] = v;
    __syncthreads();
    for (int off = 1; off < 1024; off <<= 1) {
      int tv = (tid >= off) ? buf[tid - off] : 0;
      __syncthreads();
      buf[tid] += tv;
      __syncthreads();
    }
    if (i < N_) row_ptr[i + 1] = carry + buf[tid];
    __syncthreads();
    if (tid == 0) carry += buf[1023];
    __syncthreads();
  }
}

__global__ void fill_kernel(const int* __restrict__ src, const int* __restrict__ dst,
                            const int* __restrict__ row_ptr, int* __restrict__ fill,
                            int* __restrict__ col) {
  int e = blockIdx.x * blockDim.x + threadIdx.x;
  if (e < E_) {
    int n = dst[e];
    int pos = row_ptr[n] + atomicAdd(&fill[n], 1);
    col[pos] = src[e];
  }
}

__global__ void dvec_kernel(const float* __restrict__ dis, const int* __restrict__ ti,
                            float* __restrict__ dvec) {
  int p = blockIdx.x * blockDim.x + threadIdx.x;
  if (p < P_) {
    int i0 = ti[p];
    int i1 = ti[P_ + p];
    dvec[p] = dis[(size_t)i0 * N_ + i1];
  }
}

// ---------------------------------------------------------------- mega kernel

struct Args {
  const float* x;
  const int* row_ptr;
  const int* col;
  const float* in_norm;
  const float* out_norm;
  const float* ruW1; const float* ruB1;
  const float* ruW2; const float* ruB2;
  const float* ruW3; const float* ruB3;
  const float* rhW1; const float* rhB1;
  const float* rhW2; const float* rhB2;
  const float* rhW3; const float* rhB3;
  const float* pW; const float* pb;
  const int* ti; const float* dvec;
  float* h; float* z; float* tA; float* tB;
  float* out;
  unsigned* slots;   // [nblk] per-block arrival flags
  unsigned* epoch;   // broadcast release flag
};

// Contention-free grid barrier (round-9: replaces 512-way atomicAdd on one
// line, which serialized ~25us/barrier at the coherence point).
// Arrival: per-block sc1 STORE to own slot (parallel, no RMW).
// Detection: block 0's threads poll one slot each (coalesced reads).
// Release: block 0 publishes epoch; others spin-read epoch (read-only).
// Visibility: data stores drained (vmcnt0 @ __syncthreads) before slot store;
// slots observed before epoch set; consumers read after epoch — all sc1/L3.
__device__ __forceinline__ void gbar(const Args& A, unsigned nblk, unsigned& ep) {
  __syncthreads();
  ++ep;
  const int tid = threadIdx.x;
  if (blockIdx.x == 0) {
    if (tid > 0 && tid < (int)nblk) {
      while (__hip_atomic_load(&A.slots[tid], __ATOMIC_RELAXED, SCOPE_AGENT) < ep)
        __builtin_amdgcn_s_sleep(2);
    }
    __syncthreads();
    if (tid == 0)
      __hip_atomic_store(A.epoch, ep, __ATOMIC_RELAXED, SCOPE_AGENT);
  } else {
    if (tid == 0) {
      __hip_atomic_store(&A.slots[blockIdx.x], ep, __ATOMIC_RELAXED, SCOPE_AGENT);
      while (__hip_atomic_load(A.epoch, __ATOMIC_RELAXED, SCOPE_AGENT) < ep)
        __builtin_amdgcn_s_sleep(2);
    }
    __syncthreads();
  }
}

__device__ __forceinline__ void stageW(const float* __restrict__ W, int n4,
                                       float4* __restrict__ sdst, int tid) {
  const float4* Wv = (const float4*)W;
  for (int i = tid; i < n4; i += 512) sdst[i] = Wv[i];
}

// CSR gather of 64-wide rows from tsrc via sc1 dwordx4 loads, 8 in flight
// (covers a full average-degree node in one wait). Tail slots read per-node
// zero rows (rows N_..N_+63) to stay branch-free without a hot line.
__device__ __forceinline__ float4 gatherNode(const float* __restrict__ tsrc,
                                             const int* __restrict__ rp,
                                             const int* __restrict__ col,
                                             int n, int g, int sub) {
  const int zrow = N_ + (n & (NZROWS - 1));
  int e0 = rp[n], e1 = rp[n + 1];
  f32x4 acc = {0.f, 0.f, 0.f, 0.f};
  int e = e0 + g;
  while (e < e1) {
    int c0 = col[e];
    int c1 = (e + 4  < e1) ? col[e + 4]  : zrow;
    int c2 = (e + 8  < e1) ? col[e + 8]  : zrow;
    int c3 = (e + 12 < e1) ? col[e + 12] : zrow;
    int c4 = (e + 16 < e1) ? col[e + 16] : zrow;
    int c5 = (e + 20 < e1) ? col[e + 20] : zrow;
    int c6 = (e + 24 < e1) ? col[e + 24] : zrow;
    int c7 = (e + 28 < e1) ? col[e + 28] : zrow;
    f32x4 v0 = ld4sc(tsrc + (size_t)c0 * 64 + 4 * sub);
    f32x4 v1 = ld4sc(tsrc + (size_t)c1 * 64 + 4 * sub);
    f32x4 v2 = ld4sc(tsrc + (size_t)c2 * 64 + 4 * sub);
    f32x4 v3 = ld4sc(tsrc + (size_t)c3 * 64 + 4 * sub);
    f32x4 v4 = ld4sc(tsrc + (size_t)c4 * 64 + 4 * sub);
    f32x4 v5 = ld4sc(tsrc + (size_t)c5 * 64 + 4 * sub);
    f32x4 v6 = ld4sc(tsrc + (size_t)c6 * 64 + 4 * sub);
    f32x4 v7 = ld4sc(tsrc + (size_t)c7 * 64 + 4 * sub);
    e += 32;
    vmwait0();
    acc += ((v0 + v1) + (v2 + v3)) + ((v4 + v5) + (v6 + v7));
  }
  float ax = acc.x, ay = acc.y, az = acc.z, aw = acc.w;
#pragma unroll
  for (int off = 16; off < 64; off <<= 1) {
    ax += __shfl_xor(ax, off);
    ay += __shfl_xor(ay, off);
    az += __shfl_xor(az, off);
    aw += __shfl_xor(aw, off);
  }
  return make_float4(ax, ay, az, aw);
}

__device__ __forceinline__ void predPhase(const Args& A, int t, int wgid, int WT,
                                          int g, int sub) {
  const float2* pw2 = (const float2*)A.pW;
  float2 w00 = pw2[sub],      w01 = pw2[16 + sub];
  float2 w10 = pw2[32 + sub], w11 = pw2[48 + sub];
  for (int q = wgid; q * 4 < P_; q += WT) {
    int p = q * 4 + g;
    bool valid = (p < P_);
    int i0 = valid ? A.ti[p] : 0;
    int i1 = valid ? A.ti[P_ + p] : 0;
    const float* h0 = A.h + (size_t)i0 * 64 + 2 * sub;
    const float* h1 = A.h + (size_t)i1 * 64 + 2 * sub;
    float2 a00 = ldsc2(h0), a01 = ldsc2(h0 + 32);
    float2 a10 = ldsc2(h1), a11 = ldsc2(h1 + 32);
    float part = a00.x * w00.x + a00.y * w00.y + a01.x * w01.x + a01.y * w01.y
               + a10.x * w10.x + a10.y * w10.y + a11.x * w11.x + a11.y * w11.y;
#pragma unroll
    for (int off = 1; off < 16; off <<= 1) part += __shfl_xor(part, off);
    if (valid && sub == 0) {
      float a = part + A.pb[0] + A.dvec[p] * A.pW[128];
      stsc(A.out + (size_t)p * T_ + t, tanhf(a));
    }
  }
}

// MODE 0: tdst[n] = (out_norm*relu(in_norm*agg + bias)) @ W      (W 64x64)
// MODE 1: tdst[n] = out_norm*relu(in_norm*agg + bias)            (no W)
// MODE 2: a = (in_norm*agg)@W + bias (64->128); r,z=sigmoid; z->A.z;
//         hr=r*h; fused pre: tdst[n] = (out_norm*[hr|xt]) @ Wpre
// MODE 3: a = (in_norm*agg)@W + bias (64->64); hn=tanh; h=z*h+(1-z)*hn;
//         if doPre: tdst[n] = (out_norm*[h_new|xnext]) @ Wpre
template<int MODE>
__device__ __forceinline__ void runPhase(
    const Args& A, const float* __restrict__ tsrc, float* __restrict__ tdst,
    const float* __restrict__ W, const float* __restrict__ bias,
    const float* __restrict__ Wpre, const float* __restrict__ xside,
    float4* sWv, float4* sWpreV, float (*sRow)[96], float4 (*sAgg4)[16],
    int tid, int nodeBase, int nodeEnd, bool doPre) {
  const int wave = tid >> 6;
  const int lane = tid & 63;
  const int g = lane >> 4;
  const int sub = lane & 15;

  if (MODE == 0) stageW(W, 64 * 64 / 4, sWv, tid);
  if (MODE == 2) { stageW(W, 64 * 128 / 4, sWv, tid); stageW(Wpre, 96 * 64 / 4, sWpreV, tid); }
  if (MODE == 3) { stageW(W, 64 * 64 / 4, sWv, tid); if (doPre) stageW(Wpre, 96 * 64 / 4, sWpreV, tid); }
  if (MODE != 1) __syncthreads();

  const float* sW = (const float*)sWv;
  const float* sWpre = (const float*)sWpreV;

  float4 b4 = make_float4(0.f, 0.f, 0.f, 0.f);
  float b0 = 0.f, b1 = 0.f;
  if (MODE == 0 || MODE == 1) {
    b4 = ((const float4*)bias)[sub];
  } else if (MODE == 2) {
    b0 = bias[lane]; b1 = bias[64 + lane];
  } else {
    b0 = bias[lane];
  }

  for (int n = nodeBase + wave; n < nodeEnd; n += 8) {
    float4 acc = gatherNode(tsrc, A.row_ptr, A.col, n, g, sub);
    float inn = A.in_norm[n];
    float on = A.out_norm[n];

    if (MODE == 0 || MODE == 1) {
      float4 val;
      val.x = on * fmaxf(inn * acc.x + b4.x, 0.0f);
      val.y = on * fmaxf(inn * acc.y + b4.y, 0.0f);
      val.z = on * fmaxf(inn * acc.z + b4.z, 0.0f);
      val.w = on * fmaxf(inn * acc.w + b4.w, 0.0f);
      if (MODE == 1) {
        if (g == 0) {
          f32x4 vv = {val.x, val.y, val.z, val.w};
          stsc16(tdst + (size_t)n * 64 + 4 * sub, vv);
        }
      } else {
        if (g == 0) sAgg4[wave][sub] = val;
        const float* sAgg = (const float*)&sAgg4[wave][0];
        float a = 0.0f;
#pragma unroll 8
        for (int i = 0; i < 64; ++i) a += sAgg[i] * sW[i * 64 + lane];
        stsc(tdst + (size_t)n * 64 + lane, a);
      }
    } else if (MODE == 2) {
      if (g == 0) {
        float4 val;
        val.x = inn * acc.x; val.y = inn * acc.y;
        val.z = inn * acc.z; val.w = inn * acc.w;
        sAgg4[wave][sub] = val;
      }
      const float* sAgg = (const float*)&sAgg4[wave][0];
      float a0 = b0, a1 = b1;
#pragma unroll 8
      for (int i = 0; i < 64; ++i) {
        float s = sAgg[i];
        a0 += s * sW[i * 128 + lane];
        a1 += s * sW[i * 128 + 64 + lane];
      }
      float r = 1.0f / (1.0f + expf(-a0));
      float zz = 1.0f / (1.0f + expf(-a1));
      stsc(A.z + (size_t)n * 64 + lane, zz);
      float hrv = r * ldsc(A.h + (size_t)n * 64 + lane);
      sRow[wave][lane] = on * hrv;
      if (lane < 32) sRow[wave][64 + lane] = on * xside[(size_t)n * XS_ + lane];
      float a = 0.0f;
#pragma unroll 8
      for (int i = 0; i < 96; ++i) a += sRow[wave][i] * sWpre[i * 64 + lane];
      stsc(tdst + (size_t)n * 64 + lane, a);
    } else {  // MODE 3
      if (g == 0) {
        float4 val;
        val.x = inn * acc.x; val.y = inn * acc.y;
        val.z = inn * acc.z; val.w = inn * acc.w;
        sAgg4[wave][sub] = val;
      }
      const float* sAgg = (const float*)&sAgg4[wave][0];
      float a = b0;
#pragma unroll 8
      for (int i = 0; i < 64; ++i) a += sAgg[i] * sW[i * 64 + lane];
      float hn = tanhf(a);
      float zz = ldsc(A.z + (size_t)n * 64 + lane);
      float hp = ldsc(A.h + (size_t)n * 64 + lane);
      float hnew = zz * hp + (1.0f - zz) * hn;
      stsc(A.h + (size_t)n * 64 + lane, hnew);
      if (doPre) {
        sRow[wave][lane] = on * hnew;
        if (lane < 32) sRow[wave][64 + lane] = on * xside[(size_t)n * XS_ + lane];
        float ap = 0.0f;
#pragma unroll 8
        for (int i = 0; i < 96; ++i) ap += sRow[wave][i] * sWpre[i * 64 + lane];
        stsc(tdst + (size_t)n * 64 + lane, ap);
      }
    }
  }
}

__global__ __launch_bounds__(512, 4) void mega_kernel(Args A) {
  __shared__ float4 sWv[2048];      // 32 KB: per-phase main W
  __shared__ float4 sWpreV[1536];   // 24 KB: fused 96x64 pre W
  __shared__ float sRow[8][96];     // 3 KB
  __shared__ float4 sAgg4[8][16];   // 2 KB

  const int tid = threadIdx.x;
  const int wave = tid >> 6;
  const int lane = tid & 63;
  const int g = lane >> 4;
  const int sub = lane & 15;
  const unsigned nblk = gridDim.x;
  const int NPB = (N_ + nblk - 1) / nblk;
  const int nodeBase = blockIdx.x * NPB;
  int nodeEnd = nodeBase + NPB;
  if (nodeEnd > N_) nodeEnd = N_;
  const int wgid = blockIdx.x * 8 + wave;
  const int WT = nblk * 8;
  unsigned ep = 0;

  // ---- P0: tA = (out_norm*[0|x0]) @ ru_W1  (h = 0)
  stageW(A.ruW1, 96 * 64 / 4, sWpreV, tid);
  __syncthreads();
  {
    const float* sWpre = (const float*)sWpreV;
    for (int n = nodeBase + wave; n < nodeEnd; n += 8) {
      float on = A.out_norm[n];
      if (lane < 32) sRow[wave][64 + lane] = on * A.x[(size_t)n * XS_ + lane];
      float a = 0.0f;
#pragma unroll 8
      for (int i = 64; i < 96; ++i) a += sRow[wave][i] * sWpre[i * 64 + lane];
      stsc(A.tA + (size_t)n * 64 + lane, a);
    }
  }
  gbar(A, nblk, ep);

  for (int t = 0; t < T_; ++t) {
    const float* xt  = A.x + (size_t)t * N_ * XS_;
    const float* xt1 = A.x + (size_t)(t + 1) * N_ * XS_;

    // P1: tA -> tB (ru layer1->2, pre-transformed) ; plus pred of step t-1
    runPhase<0>(A, A.tA, A.tB, A.ruW2, A.ruB1, nullptr, nullptr,
                sWv, sWpreV, sRow, sAgg4, tid, nodeBase, nodeEnd, false);
    if (t > 0) predPhase(A, t - 1, wgid, WT, g, sub);
    gbar(A, nblk, ep);

    // P2: tB -> tA (ru layer2 act only)
    runPhase<1>(A, A.tB, A.tA, nullptr, A.ruB2, nullptr, nullptr,
                sWv, sWpreV, sRow, sAgg4, tid, nodeBase, nodeEnd, false);
    gbar(A, nblk, ep);

    // P3: tA -> (z, hr) ; fused pre_rh -> tB
    runPhase<2>(A, A.tA, A.tB, A.ruW3, A.ruB3, A.rhW1, xt,
                sWv, sWpreV, sRow, sAgg4, tid, nodeBase, nodeEnd, false);
    gbar(A, nblk, ep);

    // P4: tB -> tA (rh layer1->2)
    runPhase<0>(A, A.tB, A.tA, A.rhW2, A.rhB1, nullptr, nullptr,
                sWv, sWpreV, sRow, sAgg4, tid, nodeBase, nodeEnd, false);
    gbar(A, nblk, ep);

    // P5: tA -> tB (rh layer2 act only)
    runPhase<1>(A, A.tA, A.tB, nullptr, A.rhB2, nullptr, nullptr,
                sWv, sWpreV, sRow, sAgg4, tid, nodeBase, nodeEnd, false);
    gbar(A, nblk, ep);

    // P6: tB -> h update ; fused pre_ru(t+1) -> tA
    runPhase<3>(A, A.tB, A.tA, A.rhW3, A.rhB3, A.ruW1, xt1,
                sWv, sWpreV, sRow, sAgg4, tid, nodeBase, nodeEnd, t < T_ - 1);
    gbar(A, nblk, ep);
  }

  // final prediction for t = T-1
  predPhase(A, T_ - 1, wgid, WT, g, sub);
}

// ---------------------------------------------------------------- launch

extern "C" void kernel_launch(void* const* d_in, const int* in_sizes, int n_in,
                              void* d_out, int out_size, void* d_ws, size_t ws_size,
                              hipStream_t stream) {
  const float* x      = (const float*)d_in[0];
  const float* dis    = (const float*)d_in[1];
  const int*   src    = (const int*)d_in[2];
  const int*   dst    = (const int*)d_in[3];
  const int*   ti     = (const int*)d_in[4];
  const float* ru_W1  = (const float*)d_in[5];
  const float* ru_b1  = (const float*)d_in[6];
  const float* ru_W2  = (const float*)d_in[7];
  const float* ru_b2  = (const float*)d_in[8];
  const float* ru_W3  = (const float*)d_in[9];
  const float* ru_b3  = (const float*)d_in[10];
  const float* rh_W1  = (const float*)d_in[11];
  const float* rh_b1  = (const float*)d_in[12];
  const float* rh_W2  = (const float*)d_in[13];
  const float* rh_b2  = (const float*)d_in[14];
  const float* rh_W3  = (const float*)d_in[15];
  const float* rh_b3  = (const float*)d_in[16];
  const float* pred_W = (const float*)d_in[17];
  const float* pred_b = (const float*)d_in[18];
  float* out = (float*)d_out;

  char* w = (char*)d_ws;
  auto alloc = [&](size_t bytes) -> void* {
    void* p = (void*)w;
    w += (bytes + 255) & ~(size_t)255;
    return p;
  };
  int*   row_ptr  = (int*)alloc((N_ + 1) * sizeof(int));
  int*   colv     = (int*)alloc(E_ * sizeof(int));
  int*   deg_in   = (int*)alloc(N_ * sizeof(int));
  int*   deg_out  = (int*)alloc(N_ * sizeof(int));
  int*   fillc    = (int*)alloc(N_ * sizeof(int));
  float* in_norm  = (float*)alloc(N_ * sizeof(float));
  float* out_norm = (float*)alloc(N_ * sizeof(float));
  float* dvec     = (float*)alloc(P_ * sizeof(float));
  float* h        = (float*)alloc((size_t)N_ * D_ * sizeof(float));
  float* z        = (float*)alloc((size_t)N_ * D_ * sizeof(float));
  float* tA       = (float*)alloc((size_t)(N_ + NZROWS) * D_ * sizeof(float));
  float* tB       = (float*)alloc((size_t)(N_ + NZROWS) * D_ * sizeof(float));
  unsigned* slots = (unsigned*)alloc(1024 * sizeof(unsigned));
  unsigned* epoch = (unsigned*)alloc(256);

  (void)hipMemsetAsync(deg_in, 0, N_ * sizeof(int), stream);
  (void)hipMemsetAsync(deg_out, 0, N_ * sizeof(int), stream);
  (void)hipMemsetAsync(fillc, 0, N_ * sizeof(int), stream);
  (void)hipMemsetAsync(h, 0, (size_t)N_ * D_ * sizeof(float), stream);
  (void)hipMemsetAsync(tA + (size_t)N_ * D_, 0, (size_t)NZROWS * D_ * sizeof(float), stream);
  (void)hipMemsetAsync(tB + (size_t)N_ * D_, 0, (size_t)NZROWS * D_ * sizeof(float), stream);
  (void)hipMemsetAsync(slots, 0, 1024 * sizeof(unsigned), stream);
  (void)hipMemsetAsync(epoch, 0, 256, stream);

  deg_kernel<<<(E_ + 255) / 256, 256, 0, stream>>>(src, dst, deg_out, deg_in);
  norm_kernel<<<(N_ + 255) / 256, 256, 0, stream>>>(deg_in, deg_out, in_norm, out_norm);
  scan_kernel<<<1, 1024, 0, stream>>>(deg_in, row_ptr);
  fill_kernel<<<(E_ + 255) / 256, 256, 0, stream>>>(src, dst, row_ptr, fillc, colv);
  dvec_kernel<<<(P_ + 255) / 256, 256, 0, stream>>>(dis, ti, dvec);

  Args a;
  a.x = x; a.row_ptr = row_ptr; a.col = colv;
  a.in_norm = in_norm; a.out_norm = out_norm;
  a.ruW1 = ru_W1; a.ruB1 = ru_b1; a.ruW2 = ru_W2; a.ruB2 = ru_b2;
  a.ruW3 = ru_W3; a.ruB3 = ru_b3;
  a.rhW1 = rh_W1; a.rhB1 = rh_b1; a.rhW2 = rh_W2; a.rhB2 = rh_b2;
  a.rhW3 = rh_W3; a.rhB3 = rh_b3;
  a.pW = pred_W; a.pb = pred_b; a.ti = ti; a.dvec = dvec;
  a.h = h; a.z = z; a.tA = tA; a.tB = tB; a.out = out;
  a.slots = slots; a.epoch = epoch;

  // Grid must be co-resident (round-3 lesson: over-subscribed cooperative
  // launch fails silently -> zero output). Size from the occupancy API.
  int maxb = 0;
  (void)hipOccupancyMaxActiveBlocksPerMultiprocessor(&maxb, mega_kernel, 512, 0);
  if (maxb < 1) maxb = 1;
  int bpc = (maxb < 2) ? maxb : 2;
  int nblk = 256 * bpc;   // <= 512 == blockDim, so block 0 covers all slots

  void* params[] = { (void*)&a };
  hipError_t err = hipLaunchCooperativeKernel((const void*)mega_kernel, dim3(nblk),
                                              dim3(512), params, 0, stream);
  if (err != hipSuccess) {
    // Barrier is hand-rolled (no cg) and grid is co-resident by construction.
    mega_kernel<<<dim3(nblk), dim3(512), 0, stream>>>(a);
  }
}